// Round 12
// baseline (210.863 us; speedup 1.0000x reference)
//
#include <hip/hip_runtime.h>

typedef __attribute__((ext_vector_type(8))) _Float16 f16x8;
typedef __attribute__((ext_vector_type(4))) float f32x4;

#define S4 0.35355339059327373f   /* 64^-0.25 */

static __device__ __forceinline__ ushort f2h(float f) {
  return __builtin_bit_cast(ushort, (_Float16)f);
}

static __device__ __forceinline__ void gload16(const void* g, void* l) {
  __builtin_amdgcn_global_load_lds((const __attribute__((address_space(1))) void*)g,
                                   (__attribute__((address_space(3))) void*)l, 16, 0, 0);
}

static __device__ __forceinline__ void cvt_store8(ushort* dst, float4 a, float4 b) {
  f16x8 h;
  h[0] = (_Float16)a.x; h[1] = (_Float16)a.y; h[2] = (_Float16)a.z; h[3] = (_Float16)a.w;
  h[4] = (_Float16)b.x; h[5] = (_Float16)b.y; h[6] = (_Float16)b.z; h[7] = (_Float16)b.w;
  *(f16x8*)dst = h;
}

// ---------------------------------------------------------------------------
// C[M,N] = A[M,K] @ B[N,K]^T (+ epilogue), fp16 MFMA, fp32 accum.
// EPI 0: +bias[col] -> fp16                       (Q/K projections; DIAG)
// EPI 3: +bias[col] -> fp32                       (out projection)
// EPI 4: +bias[row] -> fp16 at Vt[80-row] scatter (V^T projection)
// EPI 5: raw fp32 store                           (ctx split-K partials)
// EPI 6: 0.0625*exp(acc - rv[col]) + 1e-4 -> fp16 (phi K^T, col-diag)
// ZMODE 0: Az=A+z*sAz, Bz=B+z*sBz
// ZMODE 2: B head-sliced: Bz=B+(z>>3)*sBz+(z&7)*64
// ZMODE 3: split-K: z=(kc*16+bh): +=z&15 batch, (z>>4)*1024 along K
// DIAG 1: dg[(b*8+head)*8192+nn] = 0.0625*sum_head(v^2)  (EPI 0)
// AF32/BF32: operand is fp32 in global; reg-staged + converted to fp16 LDS
// ---------------------------------------------------------------------------
template<int BM, int BN, int WR, int WC, int EPI, int ZMODE, int DIAG, int AF32, int BF32>
__global__ __launch_bounds__(256) void gemm_bt(
    const void* __restrict__ Av, const void* __restrict__ Bv,
    const float* __restrict__ bias, ushort* __restrict__ Cb,
    float* __restrict__ Cf, const float* __restrict__ rv0,
    float* __restrict__ dg,
    int K, int ldA, int ldB, int ldC, int Mz,
    long sAz, long sBz, long sCz)
{
  constexpr int BK = 32;
  constexpr int WTM = BM / WR, WTN = BN / WC;
  constexpr int MI = WTM / 16, NI = WTN / 16;
  constexpr int LDSB = (BM + BN) * 64;

  __shared__ uint4 smem4[LDSB / 16];
  char* smem = (char*)smem4;
  ushort* As = (ushort*)smem;                 // [BM][32]
  ushort* Bs = (ushort*)(smem + BM * 64);     // [BN][32]

  const int tid = threadIdx.x;
  const int l = tid & 63, w = tid >> 6;
  const int wr = w / WC, wc = w % WC;
  const int lr = l & 15, lk = l >> 4;
  const int tm = blockIdx.x * BM, tn = blockIdx.y * BN;
  const int z = blockIdx.z;

  const ushort* Ah = (const ushort*)Av;
  const ushort* Bh = (const ushort*)Bv;
  const float*  Af = (const float*)Av;
  const float*  Bf = (const float*)Bv;
  long aoff = 0, boff = 0;
  if (ZMODE == 0) { aoff = (long)z * sAz; boff = (long)z * sBz; }
  if (ZMODE == 2) { aoff = (long)z * sAz; boff = (long)(z >> 3) * sBz + (z & 7) * 64; }
  if (ZMODE == 3) {
    aoff = (long)(z & 15) * sAz + (long)(z >> 4) * 1024;
    boff = (long)(z & 15) * sBz + (long)(z >> 4) * 1024;
  }
  Ah += aoff; Bh += boff; Af += aoff; Bf += boff;
  const float* rv = (EPI == 6) ? (rv0 + (long)z * Mz) : nullptr;
  const long coff = (long)z * sCz;

  f32x4 acc[MI][NI];
#pragma unroll
  for (int i = 0; i < MI; ++i)
#pragma unroll
    for (int j = 0; j < NI; ++j) acc[i][j] = f32x4{0.f, 0.f, 0.f, 0.f};

  for (int k0 = 0; k0 < K; k0 += BK) {
    if constexpr (AF32) {
      const int ar = tid >> 1, ac = (tid & 1) * 16;
      const float* g = Af + (long)(tm + ar) * ldA + k0 + ac;
      float4 f0 = *(const float4*)(g);
      float4 f1 = *(const float4*)(g + 4);
      float4 f2 = *(const float4*)(g + 8);
      float4 f3 = *(const float4*)(g + 12);
      cvt_store8(As + ar * 32 + ac, f0, f1);
      cvt_store8(As + ar * 32 + ac + 8, f2, f3);
    } else {
      constexpr int AB = BM * 64;
#pragma unroll
      for (int s = 0; s < (AB + 4095) / 4096; ++s) {
        const int base = s * 4096 + w * 1024;
        if (base < AB) {
          const int idx = base + l * 16;
          gload16(Ah + (long)(tm + (idx >> 6)) * ldA + k0 + ((idx & 63) >> 1),
                  (char*)As + base);
        }
      }
    }
    if constexpr (BF32) {
      const int br = tid >> 1, bc = (tid & 1) * 16;
      const float* g = Bf + (long)(tn + br) * ldB + k0 + bc;
      float4 f0 = *(const float4*)(g);
      float4 f1 = *(const float4*)(g + 4);
      float4 f2 = *(const float4*)(g + 8);
      float4 f3 = *(const float4*)(g + 12);
      cvt_store8(Bs + br * 32 + bc, f0, f1);
      cvt_store8(Bs + br * 32 + bc + 8, f2, f3);
    } else {
      constexpr int BB = BN * 64;
#pragma unroll
      for (int s = 0; s < (BB + 4095) / 4096; ++s) {
        const int base = s * 4096 + w * 1024;
        if (base < BB) {
          const int idx = base + l * 16;
          gload16(Bh + (long)(tn + (idx >> 6)) * ldB + k0 + ((idx & 63) >> 1),
                  (char*)Bs + base);
        }
      }
    }
    __syncthreads();

    f16x8 af[MI], bfr[NI];
#pragma unroll
    for (int mi = 0; mi < MI; ++mi)
      af[mi] = *(const f16x8*)(As + (wr * WTM + mi * 16 + lr) * 32 + lk * 8);
#pragma unroll
    for (int ni = 0; ni < NI; ++ni)
      bfr[ni] = *(const f16x8*)(Bs + (wc * WTN + ni * 16 + lr) * 32 + lk * 8);
#pragma unroll
    for (int mi = 0; mi < MI; ++mi)
#pragma unroll
      for (int ni = 0; ni < NI; ++ni)
        acc[mi][ni] = __builtin_amdgcn_mfma_f32_16x16x32_f16(af[mi], bfr[ni], acc[mi][ni], 0, 0, 0);
    __syncthreads();
  }

#pragma unroll
  for (int mi = 0; mi < MI; ++mi) {
#pragma unroll
    for (int j = 0; j < 4; ++j) {
      const int row = tm + wr * WTM + mi * 16 + lk * 4 + j;
      float ds = 0.f;
#pragma unroll
      for (int ni = 0; ni < NI; ++ni) {
        const int col = tn + wc * WTN + ni * 16 + lr;
        float v = acc[mi][ni][j];
        if (EPI == 0 || EPI == 3) v += bias[col];
        if (EPI == 4) v += bias[row];
        if (EPI == 6) v = 0.0625f * __expf(v - rv[col]) + 1e-4f;
        if (DIAG) ds += v * v;
        if (EPI == 4) {
          const int b = col >> 13, nn = col & 8191;
          const int h = row >> 6, d = row & 63;
          Cb[(long)(b * 8 + h) * 655360 + (long)d * 8192 + nn] = f2h(v);
        } else if (EPI == 3 || EPI == 5) {
          Cf[coff + (long)row * ldC + col] = v;
        } else {
          Cb[coff + (long)row * ldC + col] = f2h(v);
        }
      }
      if (DIAG) {
        ds += __shfl_xor(ds, 1, 64);
        ds += __shfl_xor(ds, 2, 64);
        ds += __shfl_xor(ds, 4, 64);
        ds += __shfl_xor(ds, 8, 64);
        if (lr == 0) {
          const int b = row >> 13, nn = row & 8191;
          const int head = (tn + wc * WTN) >> 6;
          dg[(long)(b * 8 + head) * 8192 + nn] = 0.0625f * ds;
        }
      }
    }
  }
}

// ---------------------------------------------------------------------------
// phiattn_k: fused phi(Q) + attn(+denom), 64-row blocks, 45 KB LDS
// (3 blocks/CU). ctxb B-fragments read from global (L1/L2-hot: consecutive
// blocks share bh). grid (bx<128, bh<16).
// ---------------------------------------------------------------------------
__global__ __launch_bounds__(256) void phiattn_k(
    const ushort* __restrict__ Qh, const ushort* __restrict__ pjh,
    const float* __restrict__ diagQ, const ushort* __restrict__ ctxb,
    ushort* __restrict__ attnR)
{
  const int bx = blockIdx.x, bh = blockIdx.y;
  const int b = bh >> 3, h = bh & 7;
  const int tm = bx * 64;
  const int tid = threadIdx.x, l = tid & 63, w = tid >> 6;
  const int lr = l & 15, lk = l >> 4;

  __shared__ char smem[46080];
  ushort* P  = (ushort*)smem;              // [64][264] (warp w owns rows w*16..+15)
  ushort* As = (ushort*)(smem + 33792);    // [64][32]
  ushort* Bs = (ushort*)(smem + 37888);    // [128][32]

  const ushort* QB = Qh + (long)b * 4194304 + h * 64;
  const float* rv = diagQ + (long)bh * 8192;

  // ---- phi(Q): two 64x128 halves ----
  for (int nh = 0; nh < 2; ++nh) {
    const ushort* PB = pjh + nh * 8192;
    f32x4 a2[8];
#pragma unroll
    for (int i = 0; i < 8; ++i) a2[i] = f32x4{0.f, 0.f, 0.f, 0.f};

    for (int k0 = 0; k0 < 64; k0 += 32) {
      {   // stage As: 4096 B (one chunk)
        const int base = w * 1024;
        const int idx = base + l * 16;
        gload16(QB + (long)(tm + (idx >> 6)) * 512 + k0 + ((idx & 63) >> 1),
                (char*)As + base);
      }
#pragma unroll
      for (int s = 0; s < 2; ++s) {   // stage Bs: 8192 B
        const int base = s * 4096 + w * 1024;
        const int idx = base + l * 16;
        gload16(PB + (long)(idx >> 6) * 64 + k0 + ((idx & 63) >> 1),
                (char*)Bs + base);
      }
      __syncthreads();
      f16x8 af = *(const f16x8*)(As + (w * 16 + lr) * 32 + lk * 8);
#pragma unroll
      for (int ni = 0; ni < 8; ++ni) {
        f16x8 bfr = *(const f16x8*)(Bs + (ni * 16 + lr) * 32 + lk * 8);
        a2[ni] = __builtin_amdgcn_mfma_f32_16x16x32_f16(af, bfr, a2[ni], 0, 0, 0);
      }
      __syncthreads();
    }
    // exp epilogue -> P (own warp strip only)
#pragma unroll
    for (int ni = 0; ni < 8; ++ni)
#pragma unroll
      for (int j = 0; j < 4; ++j) {
        const int row = w * 16 + lk * 4 + j;
        const int col = nh * 128 + ni * 16 + lr;
        const float vv = 0.0625f * __expf(a2[ni][j] - rv[tm + row]) + 1e-4f;
        P[row * 264 + col] = f2h(vv);
      }
  }
  __syncthreads();

  // ---- attn: C[64 n][80] = P @ ctxb^T, B from global, fused denom ----
  f32x4 acc[5];
#pragma unroll
  for (int i = 0; i < 5; ++i) acc[i] = f32x4{0.f, 0.f, 0.f, 0.f};

  const ushort* cb = ctxb + (long)bh * 20480;
  for (int k0 = 0; k0 < 256; k0 += 32) {
    f16x8 pa = *(const f16x8*)(P + (w * 16 + lr) * 264 + k0 + lk * 8);
#pragma unroll
    for (int ni = 0; ni < 5; ++ni) {
      f16x8 cf = *(const f16x8*)(cb + (long)(ni * 16 + lr) * 256 + k0 + lk * 8);
      acc[ni] = __builtin_amdgcn_mfma_f32_16x16x32_f16(pa, cf, acc[ni], 0, 0, 0);
    }
  }

  ushort* outb = attnR + (long)bh * 524288;
#pragma unroll
  for (int j = 0; j < 4; ++j) {
    const float dv = __shfl(acc[4][j], (l & 48), 64);
    const int row = tm + w * 16 + lk * 4 + j;
#pragma unroll
    for (int ni = 0; ni < 4; ++ni) {
      const int col = ni * 16 + lr;
      outb[(long)row * 64 + col] = f2h(acc[ni][j] / dv);
    }
  }
}

// merged fp32 -> fp16 weight conversions (wq,wk,wv,wo,pj*S4)
__global__ __launch_bounds__(256) void cvtall_k(
    const float* __restrict__ wq, const float* __restrict__ wk,
    const float* __restrict__ wv, const float* __restrict__ wo,
    const float* __restrict__ pj,
    ushort* __restrict__ wqh, ushort* __restrict__ wkh,
    ushort* __restrict__ wvh, ushort* __restrict__ woh,
    ushort* __restrict__ pjh)
{
  int i = blockIdx.x * 256 + threadIdx.x;   // 266240 total float4 groups
  const float* in; ushort* out; float scale = 1.f; int idx;
  if (i < 65536)       { in = wq; out = wqh; idx = i; }
  else if (i < 131072) { in = wk; out = wkh; idx = i - 65536; }
  else if (i < 196608) { in = wv; out = wvh; idx = i - 131072; }
  else if (i < 262144) { in = wo; out = woh; idx = i - 196608; }
  else if (i < 266240) { in = pj; out = pjh; idx = i - 262144; scale = S4; }
  else return;
  float4 v = ((const float4*)in)[idx];
  ushort4 o;
  o.x = f2h(v.x * scale); o.y = f2h(v.y * scale);
  o.z = f2h(v.z * scale); o.w = f2h(v.w * scale);
  ((ushort4*)out)[idx] = o;
}

// fill Vt rows 64..79: row 64 = 1.0 (ksum ones-row), 65..79 = 0
__global__ __launch_bounds__(256) void vtpad_k(ushort* __restrict__ Vt) {
  const int i = blockIdx.x * 256 + threadIdx.x;
  const int bh = i >> 14, rem = i & 16383, r = rem >> 10, n8 = rem & 1023;
  const unsigned val = (r == 0) ? 0x3C003C00u : 0u;
  uint4 u; u.x = val; u.y = val; u.z = val; u.w = val;
  *(uint4*)(Vt + (long)bh * 655360 + (long)(64 + r) * 8192 + n8 * 8) = u;
}

// reduce 8 ctx split-K partials -> fp16 ctxb[bh][80][256] (row 64 = ksum)
__global__ __launch_bounds__(256) void ctxred_k(const float* __restrict__ cp,
                                                ushort* __restrict__ ctxb) {
  const int idx = blockIdx.x * 256 + threadIdx.x;   // 327680
  const int bh = idx / 20480, rem = idx % 20480;
  float a = 0.f;
#pragma unroll
  for (int kc = 0; kc < 8; ++kc) a += cp[(long)(kc * 16 + bh) * 20480 + rem];
  ctxb[idx] = f2h(a);
}

extern "C" void kernel_launch(void* const* d_in, const int* in_sizes, int n_in,
                              void* d_out, int out_size, void* d_ws, size_t ws_size,
                              hipStream_t stream) {
  (void)in_sizes; (void)n_in; (void)out_size; (void)ws_size;
  const float* q  = (const float*)d_in[0];
  const float* k  = (const float*)d_in[1];
  const float* v  = (const float*)d_in[2];
  const float* wq = (const float*)d_in[3];
  const float* bq = (const float*)d_in[4];
  const float* wk = (const float*)d_in[5];
  const float* bk = (const float*)d_in[6];
  const float* wv = (const float*)d_in[7];
  const float* bv = (const float*)d_in[8];
  const float* wo = (const float*)d_in[9];
  const float* bo = (const float*)d_in[10];
  const float* pj = (const float*)d_in[11];

  char* ws = (char*)d_ws;
  ushort* attnR = (ushort*)(ws + 0);          // [16][8192][64]
  float*  cpart = (float*)(ws + 16777216);    // [128][80][256] fp32
  ushort* wqh   = (ushort*)(ws + 27262976);
  ushort* wkh   = (ushort*)(ws + 27787264);
  ushort* wvh   = (ushort*)(ws + 28311552);
  ushort* woh   = (ushort*)(ws + 28835840);
  ushort* pjh   = (ushort*)(ws + 29360128);
  ushort* Qh    = (ushort*)(ws + 29392896);   // [16384][512]
  ushort* Kh    = (ushort*)(ws + 46170112);   // [16384][512]
  ushort* Vt    = (ushort*)(ws + 62947328);   // [16][80][8192] (row64=1s)
  ushort* KpT   = (ushort*)(ws + 83918848);   // [16][256][8192]
  float*  diagQ = (float*)(ws + 151027712);
  float*  diagK = (float*)(ws + 151552000);
  ushort* ctxb  = (ushort*)(ws + 152076288);  // [16][80][256] (row64=ksum)

  // 1. merged weight conversions + Vt pad rows
  cvtall_k<<<1040, 256, 0, stream>>>(wq, wk, wv, wo, pj, wqh, wkh, wvh, woh, pjh);
  vtpad_k<<<1024, 256, 0, stream>>>(Vt);

  // 2. Q/K projections (fp32 A reg-staged, +bias, fused diag)
  gemm_bt<128,128,2,2,0,0,1,1,0><<<dim3(128,4,1), 256, 0, stream>>>(
      q, wqh, bq, Qh, nullptr, nullptr, diagQ, 512, 512, 512, 512, 0, 0L, 0L, 0L);
  gemm_bt<128,128,2,2,0,0,1,1,0><<<dim3(128,4,1), 256, 0, stream>>>(
      k, wkh, bk, Kh, nullptr, nullptr, diagK, 512, 512, 512, 512, 0, 0L, 0L, 0L);

  // 3. V^T projection (fp32 B reg-staged) -> Vt[bh][d][n]
  gemm_bt<128,128,2,2,4,0,0,0,1><<<dim3(4,128,1), 256, 0, stream>>>(
      wvh, v, bv, Vt, nullptr, nullptr, nullptr, 512, 512, 512, 0, 0, 0L, 0L, 0L);

  // 4. phi(K)^T: C[m=256][n=8192] per bh -> KpT (col-diag exp epilogue)
  gemm_bt<128,128,2,2,6,2,0,0,0><<<dim3(2,64,16), 256, 0, stream>>>(
      pjh, Kh, nullptr, KpT, nullptr, diagK, nullptr, 64, 64, 512, 8192, 8192,
      0L, 4194304L, 2097152L);

  // 5. ctx (+ksum via ones row): C[80][m=256] = Vt @ KpT^T, split-K x8
  gemm_bt<80,128,1,4,5,3,0,0,0><<<dim3(1,2,128), 256, 0, stream>>>(
      Vt, KpT, nullptr, nullptr, cpart, nullptr, nullptr, 1024, 8192, 8192, 256, 0,
      655360L, 2097152L, 20480L);
  ctxred_k<<<1280, 256, 0, stream>>>(cpart, ctxb);

  // 6. fused phi(Q)+attn(+denom), 64-row blocks -> attnR
  phiattn_k<<<dim3(128,16), 256, 0, stream>>>(Qh, pjh, diagQ, ctxb, attnR);

  // 7. output projection (+bias) -> fp32 d_out
  gemm_bt<128,128,2,2,3,0,0,0,0><<<dim3(128,4,1), 256, 0, stream>>>(
      attnR, woh, bo, nullptr, (float*)d_out, nullptr, nullptr, 512, 512, 512, 512, 0,
      0L, 0L, 0L);
}

// Round 13
// 187.345 us; speedup vs baseline: 1.1255x; 1.1255x over previous
//
#include <hip/hip_runtime.h>

typedef __attribute__((ext_vector_type(8))) _Float16 f16x8;
typedef __attribute__((ext_vector_type(4))) float f32x4;

#define S4 0.35355339059327373f   /* 64^-0.25 */

static __device__ __forceinline__ ushort f2h(float f) {
  return __builtin_bit_cast(ushort, (_Float16)f);
}

static __device__ __forceinline__ void gload16(const void* g, void* l) {
  __builtin_amdgcn_global_load_lds((const __attribute__((address_space(1))) void*)g,
                                   (__attribute__((address_space(3))) void*)l, 16, 0, 0);
}

static __device__ __forceinline__ void cvt_store8(ushort* dst, float4 a, float4 b) {
  f16x8 h;
  h[0] = (_Float16)a.x; h[1] = (_Float16)a.y; h[2] = (_Float16)a.z; h[3] = (_Float16)a.w;
  h[4] = (_Float16)b.x; h[5] = (_Float16)b.y; h[6] = (_Float16)b.z; h[7] = (_Float16)b.w;
  *(f16x8*)dst = h;
}

// ---------------------------------------------------------------------------
// C[M,N] = A[M,K] @ B[N,K]^T (+ epilogue), fp16 MFMA, fp32 accum.
// EPI 0: +bias[col] -> fp16                       (Q/K projections; DIAG)
// EPI 3: +bias[col] -> fp32                       (out projection)
// EPI 4: +bias[row] -> fp16 at Vt[80-row] scatter (V^T projection)
// EPI 5: raw fp32 store                           (ctx split-K partials)
// EPI 6: 0.0625*exp(acc - rv[col]) + 1e-4 -> fp16 (phi K^T, col-diag)
// ZMODE 0: Az=A+z*sAz, Bz=B+z*sBz
// ZMODE 2: B head-sliced: Bz=B+(z>>3)*sBz+(z&7)*64
// ZMODE 3: split-K: z=(kc*16+bh): +=z&15 batch, (z>>4)*1024 along K
// DIAG 1: dg[(b*8+head)*8192+nn] = 0.0625*sum_head(v^2)  (EPI 0)
// AF32/BF32: operand is fp32 in global; reg-staged + converted to fp16 LDS
// ---------------------------------------------------------------------------
template<int BM, int BN, int WR, int WC, int EPI, int ZMODE, int DIAG, int AF32, int BF32>
__global__ __launch_bounds__(256) void gemm_bt(
    const void* __restrict__ Av, const void* __restrict__ Bv,
    const float* __restrict__ bias, ushort* __restrict__ Cb,
    float* __restrict__ Cf, const float* __restrict__ rv0,
    float* __restrict__ dg,
    int K, int ldA, int ldB, int ldC, int Mz,
    long sAz, long sBz, long sCz)
{
  constexpr int BK = 32;
  constexpr int WTM = BM / WR, WTN = BN / WC;
  constexpr int MI = WTM / 16, NI = WTN / 16;
  constexpr int LDSB = (BM + BN) * 64;

  __shared__ uint4 smem4[LDSB / 16];
  char* smem = (char*)smem4;
  ushort* As = (ushort*)smem;                 // [BM][32]
  ushort* Bs = (ushort*)(smem + BM * 64);     // [BN][32]

  const int tid = threadIdx.x;
  const int l = tid & 63, w = tid >> 6;
  const int wr = w / WC, wc = w % WC;
  const int lr = l & 15, lk = l >> 4;
  const int tm = blockIdx.x * BM, tn = blockIdx.y * BN;
  const int z = blockIdx.z;

  const ushort* Ah = (const ushort*)Av;
  const ushort* Bh = (const ushort*)Bv;
  const float*  Af = (const float*)Av;
  const float*  Bf = (const float*)Bv;
  long aoff = 0, boff = 0;
  if (ZMODE == 0) { aoff = (long)z * sAz; boff = (long)z * sBz; }
  if (ZMODE == 2) { aoff = (long)z * sAz; boff = (long)(z >> 3) * sBz + (z & 7) * 64; }
  if (ZMODE == 3) {
    aoff = (long)(z & 15) * sAz + (long)(z >> 4) * 1024;
    boff = (long)(z & 15) * sBz + (long)(z >> 4) * 1024;
  }
  Ah += aoff; Bh += boff; Af += aoff; Bf += boff;
  const float* rv = (EPI == 6) ? (rv0 + (long)z * Mz) : nullptr;
  const long coff = (long)z * sCz;

  f32x4 acc[MI][NI];
#pragma unroll
  for (int i = 0; i < MI; ++i)
#pragma unroll
    for (int j = 0; j < NI; ++j) acc[i][j] = f32x4{0.f, 0.f, 0.f, 0.f};

  for (int k0 = 0; k0 < K; k0 += BK) {
    if constexpr (AF32) {
      const int ar = tid >> 1, ac = (tid & 1) * 16;
      const float* g = Af + (long)(tm + ar) * ldA + k0 + ac;
      float4 f0 = *(const float4*)(g);
      float4 f1 = *(const float4*)(g + 4);
      float4 f2 = *(const float4*)(g + 8);
      float4 f3 = *(const float4*)(g + 12);
      cvt_store8(As + ar * 32 + ac, f0, f1);
      cvt_store8(As + ar * 32 + ac + 8, f2, f3);
    } else {
      constexpr int AB = BM * 64;
#pragma unroll
      for (int s = 0; s < (AB + 4095) / 4096; ++s) {
        const int base = s * 4096 + w * 1024;
        if (base < AB) {
          const int idx = base + l * 16;
          gload16(Ah + (long)(tm + (idx >> 6)) * ldA + k0 + ((idx & 63) >> 1),
                  (char*)As + base);
        }
      }
    }
    if constexpr (BF32) {
      const int br = tid >> 1, bc = (tid & 1) * 16;
      const float* g = Bf + (long)(tn + br) * ldB + k0 + bc;
      float4 f0 = *(const float4*)(g);
      float4 f1 = *(const float4*)(g + 4);
      float4 f2 = *(const float4*)(g + 8);
      float4 f3 = *(const float4*)(g + 12);
      cvt_store8(Bs + br * 32 + bc, f0, f1);
      cvt_store8(Bs + br * 32 + bc + 8, f2, f3);
    } else {
      constexpr int BB = BN * 64;
#pragma unroll
      for (int s = 0; s < (BB + 4095) / 4096; ++s) {
        const int base = s * 4096 + w * 1024;
        if (base < BB) {
          const int idx = base + l * 16;
          gload16(Bh + (long)(tn + (idx >> 6)) * ldB + k0 + ((idx & 63) >> 1),
                  (char*)Bs + base);
        }
      }
    }
    __syncthreads();

    f16x8 af[MI], bfr[NI];
#pragma unroll
    for (int mi = 0; mi < MI; ++mi)
      af[mi] = *(const f16x8*)(As + (wr * WTM + mi * 16 + lr) * 32 + lk * 8);
#pragma unroll
    for (int ni = 0; ni < NI; ++ni)
      bfr[ni] = *(const f16x8*)(Bs + (wc * WTN + ni * 16 + lr) * 32 + lk * 8);
#pragma unroll
    for (int mi = 0; mi < MI; ++mi)
#pragma unroll
      for (int ni = 0; ni < NI; ++ni)
        acc[mi][ni] = __builtin_amdgcn_mfma_f32_16x16x32_f16(af[mi], bfr[ni], acc[mi][ni], 0, 0, 0);
    __syncthreads();
  }

#pragma unroll
  for (int mi = 0; mi < MI; ++mi) {
#pragma unroll
    for (int j = 0; j < 4; ++j) {
      const int row = tm + wr * WTM + mi * 16 + lk * 4 + j;
      float ds = 0.f;
#pragma unroll
      for (int ni = 0; ni < NI; ++ni) {
        const int col = tn + wc * WTN + ni * 16 + lr;
        float v = acc[mi][ni][j];
        if (EPI == 0 || EPI == 3) v += bias[col];
        if (EPI == 4) v += bias[row];
        if (EPI == 6) v = 0.0625f * __expf(v - rv[col]) + 1e-4f;
        if (DIAG) ds += v * v;
        if (EPI == 4) {
          const int b = col >> 13, nn = col & 8191;
          const int h = row >> 6, d = row & 63;
          Cb[(long)(b * 8 + h) * 655360 + (long)d * 8192 + nn] = f2h(v);
        } else if (EPI == 3 || EPI == 5) {
          Cf[coff + (long)row * ldC + col] = v;
        } else {
          Cb[coff + (long)row * ldC + col] = f2h(v);
        }
      }
      if (DIAG) {
        ds += __shfl_xor(ds, 1, 64);
        ds += __shfl_xor(ds, 2, 64);
        ds += __shfl_xor(ds, 4, 64);
        ds += __shfl_xor(ds, 8, 64);
        if (lr == 0) {
          const int b = row >> 13, nn = row & 8191;
          const int head = (tn + wc * WTN) >> 6;
          dg[(long)(b * 8 + head) * 8192 + nn] = 0.0625f * ds;
        }
      }
    }
  }
}

// ---------------------------------------------------------------------------
// phiattn_k v3: fused phi(Q)+attn(+denom), 64-row blocks, all-LDS operands,
// 79.9 KB LDS -> 2 blocks/CU, 3 barriers total. grid (bx<128, bh<16).
// LDS: P[64][264] @0; union{ Pj[256][72] @33792 + As[64][72] @70656,
//                            Cs[80][264] @33792 } -> 79872 B.
// ---------------------------------------------------------------------------
__global__ __launch_bounds__(256) void phiattn_k(
    const ushort* __restrict__ Qh, const ushort* __restrict__ pjh,
    const float* __restrict__ diagQ, const ushort* __restrict__ ctxb,
    ushort* __restrict__ attnR)
{
  const int bx = blockIdx.x, bh = blockIdx.y;
  const int b = bh >> 3, h = bh & 7;
  const int tm = bx * 64;
  const int tid = threadIdx.x, l = tid & 63, w = tid >> 6;
  const int lr = l & 15, lk = l >> 4;

  __shared__ uint4 smem4[4992];   // 79872 B
  char* smem = (char*)smem4;
  ushort* P  = (ushort*)smem;              // [64][264]
  ushort* Pj = (ushort*)(smem + 33792);    // [256][72]
  ushort* As = (ushort*)(smem + 70656);    // [64][72]
  ushort* Cs = (ushort*)(smem + 33792);    // [80][264] (overlays Pj/As)

  const ushort* QB = Qh + (long)b * 4194304 + h * 64;
  const float* rv = diagQ + (long)bh * 8192;

  // ---- stage Pj [256][64] and As [64][64] (padded ld=72), once ----
#pragma unroll
  for (int it = 0; it < 8; ++it) {     // 2048 16B-granules of proj
    const int g = it * 256 + tid;
    const int row = g >> 3, colg = (g & 7) * 8;
    *(uint4*)(Pj + row * 72 + colg) = *(const uint4*)(pjh + row * 64 + colg);
  }
#pragma unroll
  for (int it = 0; it < 2; ++it) {     // 512 granules of Q rows
    const int g = it * 256 + tid;
    const int row = g >> 3, colg = (g & 7) * 8;
    *(uint4*)(As + row * 72 + colg) = *(const uint4*)(QB + (long)(tm + row) * 512 + colg);
  }
  __syncthreads();

  // ---- phi: C[64 n][256 m] = Q64x64 @ proj^T, all-LDS ----
  f32x4 a2[16];
#pragma unroll
  for (int i = 0; i < 16; ++i) a2[i] = f32x4{0.f, 0.f, 0.f, 0.f};
  {
    f16x8 af0 = *(const f16x8*)(As + (w * 16 + lr) * 72 + lk * 8);
    f16x8 af1 = *(const f16x8*)(As + (w * 16 + lr) * 72 + 32 + lk * 8);
#pragma unroll
    for (int ni = 0; ni < 16; ++ni) {
      f16x8 b0 = *(const f16x8*)(Pj + (ni * 16 + lr) * 72 + lk * 8);
      f16x8 b1 = *(const f16x8*)(Pj + (ni * 16 + lr) * 72 + 32 + lk * 8);
      a2[ni] = __builtin_amdgcn_mfma_f32_16x16x32_f16(af0, b0, a2[ni], 0, 0, 0);
      a2[ni] = __builtin_amdgcn_mfma_f32_16x16x32_f16(af1, b1, a2[ni], 0, 0, 0);
    }
  }
  // exp epilogue -> P (own warp strip rows w*16..w*16+15)
#pragma unroll
  for (int ni = 0; ni < 16; ++ni)
#pragma unroll
    for (int j = 0; j < 4; ++j) {
      const int row = w * 16 + lk * 4 + j;
      const int col = ni * 16 + lr;
      const float vv = 0.0625f * __expf(a2[ni][j] - rv[tm + row]) + 1e-4f;
      P[row * 264 + col] = f2h(vv);
    }
  __syncthreads();   // all Pj/As reads done

  // ---- stage Cs [80][256] (ld=264) over Pj/As ----
#pragma unroll
  for (int it = 0; it < 10; ++it) {    // 2560 granules
    const int g = it * 256 + tid;
    const int row = g >> 5, colg = (g & 31) * 8;
    *(uint4*)(Cs + row * 264 + colg) =
        *(const uint4*)(ctxb + (long)bh * 20480 + row * 256 + colg);
  }
  __syncthreads();

  // ---- attn: C[64 n][80] = P @ Cs^T, all-LDS, fused denom ----
  f32x4 acc[5];
#pragma unroll
  for (int i = 0; i < 5; ++i) acc[i] = f32x4{0.f, 0.f, 0.f, 0.f};

  for (int k0 = 0; k0 < 256; k0 += 32) {
    f16x8 pa = *(const f16x8*)(P + (w * 16 + lr) * 264 + k0 + lk * 8);
#pragma unroll
    for (int ni = 0; ni < 5; ++ni) {
      f16x8 cf = *(const f16x8*)(Cs + (ni * 16 + lr) * 264 + k0 + lk * 8);
      acc[ni] = __builtin_amdgcn_mfma_f32_16x16x32_f16(pa, cf, acc[ni], 0, 0, 0);
    }
  }

  ushort* outb = attnR + (long)bh * 524288;
#pragma unroll
  for (int j = 0; j < 4; ++j) {
    const float dv = __shfl(acc[4][j], (l & 48), 64);
    const int row = tm + w * 16 + lk * 4 + j;
#pragma unroll
    for (int ni = 0; ni < 4; ++ni) {
      const int col = ni * 16 + lr;
      outb[(long)row * 64 + col] = f2h(acc[ni][j] / dv);
    }
  }
}

// merged fp32 -> fp16 weight conversions (wq,wk,wv,wo,pj*S4)
__global__ __launch_bounds__(256) void cvtall_k(
    const float* __restrict__ wq, const float* __restrict__ wk,
    const float* __restrict__ wv, const float* __restrict__ wo,
    const float* __restrict__ pj,
    ushort* __restrict__ wqh, ushort* __restrict__ wkh,
    ushort* __restrict__ wvh, ushort* __restrict__ woh,
    ushort* __restrict__ pjh)
{
  int i = blockIdx.x * 256 + threadIdx.x;   // 266240 total float4 groups
  const float* in; ushort* out; float scale = 1.f; int idx;
  if (i < 65536)       { in = wq; out = wqh; idx = i; }
  else if (i < 131072) { in = wk; out = wkh; idx = i - 65536; }
  else if (i < 196608) { in = wv; out = wvh; idx = i - 131072; }
  else if (i < 262144) { in = wo; out = woh; idx = i - 196608; }
  else if (i < 266240) { in = pj; out = pjh; idx = i - 262144; scale = S4; }
  else return;
  float4 v = ((const float4*)in)[idx];
  ushort4 o;
  o.x = f2h(v.x * scale); o.y = f2h(v.y * scale);
  o.z = f2h(v.z * scale); o.w = f2h(v.w * scale);
  ((ushort4*)out)[idx] = o;
}

// fill Vt rows 64..79: row 64 = 1.0 (ksum ones-row), 65..79 = 0
__global__ __launch_bounds__(256) void vtpad_k(ushort* __restrict__ Vt) {
  const int i = blockIdx.x * 256 + threadIdx.x;
  const int bh = i >> 14, rem = i & 16383, r = rem >> 10, n8 = rem & 1023;
  const unsigned val = (r == 0) ? 0x3C003C00u : 0u;
  uint4 u; u.x = val; u.y = val; u.z = val; u.w = val;
  *(uint4*)(Vt + (long)bh * 655360 + (long)(64 + r) * 8192 + n8 * 8) = u;
}

// reduce 8 ctx split-K partials -> fp16 ctxb[bh][80][256] (row 64 = ksum)
__global__ __launch_bounds__(256) void ctxred_k(const float* __restrict__ cp,
                                                ushort* __restrict__ ctxb) {
  const int idx = blockIdx.x * 256 + threadIdx.x;   // 327680
  const int bh = idx / 20480, rem = idx % 20480;
  float a = 0.f;
#pragma unroll
  for (int kc = 0; kc < 8; ++kc) a += cp[(long)(kc * 16 + bh) * 20480 + rem];
  ctxb[idx] = f2h(a);
}

extern "C" void kernel_launch(void* const* d_in, const int* in_sizes, int n_in,
                              void* d_out, int out_size, void* d_ws, size_t ws_size,
                              hipStream_t stream) {
  (void)in_sizes; (void)n_in; (void)out_size; (void)ws_size;
  const float* q  = (const float*)d_in[0];
  const float* k  = (const float*)d_in[1];
  const float* v  = (const float*)d_in[2];
  const float* wq = (const float*)d_in[3];
  const float* bq = (const float*)d_in[4];
  const float* wk = (const float*)d_in[5];
  const float* bk = (const float*)d_in[6];
  const float* wv = (const float*)d_in[7];
  const float* bv = (const float*)d_in[8];
  const float* wo = (const float*)d_in[9];
  const float* bo = (const float*)d_in[10];
  const float* pj = (const float*)d_in[11];

  char* ws = (char*)d_ws;
  ushort* attnR = (ushort*)(ws + 0);          // [16][8192][64]
  float*  cpart = (float*)(ws + 16777216);    // [128][80][256] fp32
  ushort* wqh   = (ushort*)(ws + 27262976);
  ushort* wkh   = (ushort*)(ws + 27787264);
  ushort* wvh   = (ushort*)(ws + 28311552);
  ushort* woh   = (ushort*)(ws + 28835840);
  ushort* pjh   = (ushort*)(ws + 29360128);
  ushort* Qh    = (ushort*)(ws + 29392896);   // [16384][512]
  ushort* Kh    = (ushort*)(ws + 46170112);   // [16384][512]
  ushort* Vt    = (ushort*)(ws + 62947328);   // [16][80][8192] (row64=1s)
  ushort* KpT   = (ushort*)(ws + 83918848);   // [16][256][8192]
  float*  diagQ = (float*)(ws + 151027712);
  float*  diagK = (float*)(ws + 151552000);
  ushort* ctxb  = (ushort*)(ws + 152076288);  // [16][80][256] (row64=ksum)

  // 1. merged weight conversions + Vt pad rows
  cvtall_k<<<1040, 256, 0, stream>>>(wq, wk, wv, wo, pj, wqh, wkh, wvh, woh, pjh);
  vtpad_k<<<1024, 256, 0, stream>>>(Vt);

  // 2. Q/K projections (fp32 A reg-staged, +bias, fused diag)
  gemm_bt<128,128,2,2,0,0,1,1,0><<<dim3(128,4,1), 256, 0, stream>>>(
      q, wqh, bq, Qh, nullptr, nullptr, diagQ, 512, 512, 512, 512, 0, 0L, 0L, 0L);
  gemm_bt<128,128,2,2,0,0,1,1,0><<<dim3(128,4,1), 256, 0, stream>>>(
      k, wkh, bk, Kh, nullptr, nullptr, diagK, 512, 512, 512, 512, 0, 0L, 0L, 0L);

  // 3. V^T projection (fp32 B reg-staged) -> Vt[bh][d][n]
  gemm_bt<128,128,2,2,4,0,0,0,1><<<dim3(4,128,1), 256, 0, stream>>>(
      wvh, v, bv, Vt, nullptr, nullptr, nullptr, 512, 512, 512, 0, 0, 0L, 0L, 0L);

  // 4. phi(K)^T: C[m=256][n=8192] per bh -> KpT (col-diag exp epilogue)
  gemm_bt<128,128,2,2,6,2,0,0,0><<<dim3(2,64,16), 256, 0, stream>>>(
      pjh, Kh, nullptr, KpT, nullptr, diagK, nullptr, 64, 64, 512, 8192, 8192,
      0L, 4194304L, 2097152L);

  // 5. ctx (+ksum via ones row): C[80][m=256] = Vt @ KpT^T, split-K x8
  gemm_bt<80,128,1,4,5,3,0,0,0><<<dim3(1,2,128), 256, 0, stream>>>(
      Vt, KpT, nullptr, nullptr, cpart, nullptr, nullptr, 1024, 8192, 8192, 256, 0,
      655360L, 2097152L, 20480L);
  ctxred_k<<<1280, 256, 0, stream>>>(cpart, ctxb);

  // 6. fused phi(Q)+attn(+denom) v3 -> attnR
  phiattn_k<<<dim3(128,16), 256, 0, stream>>>(Qh, pjh, diagQ, ctxb, attnR);

  // 7. output projection (+bias) -> fp32 d_out
  gemm_bt<128,128,2,2,3,0,0,0,0><<<dim3(128,4,1), 256, 0, stream>>>(
      attnR, woh, bo, nullptr, (float*)d_out, nullptr, nullptr, 512, 512, 512, 512, 0,
      0L, 0L, 0L);
}